// Round 6
// baseline (344.874 us; speedup 1.0000x reference)
//
#include <hip/hip_runtime.h>
#include <hip/hip_bf16.h>
#include <math.h>

typedef __bf16 bf16;
typedef __bf16 bf16x8 __attribute__((ext_vector_type(8)));
typedef __bf16 bf16x4 __attribute__((ext_vector_type(4)));
typedef float f32x4 __attribute__((ext_vector_type(4)));
typedef unsigned short u16;
typedef u16 u16x8 __attribute__((ext_vector_type(8)));

#define SEQ 1024
#define DIMSZ 1024
#define NHEADS 16
#define HEADDIM 64
#define BATCH 4

// q-scale: 1/sqrt(64) * log2(e)  (log2e folded so softmax uses raw exp2)
#define QSCALE 0.180336880f

// ---------------- async global->LDS (16B per lane, linear dest) ----------------
typedef __attribute__((address_space(1))) const unsigned char gas_u8;
typedef __attribute__((address_space(3))) unsigned char las_u8;
__device__ __forceinline__ void gload16(const void* g, void* l) {
    __builtin_amdgcn_global_load_lds((const gas_u8*)g, (las_u8*)l, 16, 0, 0);
}

// ---------------- fp32 -> bf16 conversion with baked chunk-swizzle ----------------
// dst element (row, col) stored at chunk ^= (row&7) within each 64-col group
__device__ __forceinline__ void cvt_store(const float4 v, bf16* dst, int e0, float scale) {
    int row = e0 >> 10, col = e0 & 1023;
    int col2 = (col & ~63) | (col & 7) | (((((col >> 3) & 7) ^ (row & 7))) << 3);
    bf16x4 o;
    o[0] = (bf16)(v.x * scale);
    o[1] = (bf16)(v.y * scale);
    o[2] = (bf16)(v.z * scale);
    o[3] = (bf16)(v.w * scale);
    *reinterpret_cast<bf16x4*>(&dst[(size_t)row * 1024 + col2]) = o;
}

__global__ void cvt_swz(const float4* __restrict__ src, bf16* __restrict__ dst,
                        int n4, float scale) {
    int i = blockIdx.x * blockDim.x + threadIdx.x;
    if (i >= n4) return;
    cvt_store(src[i], dst, i << 2, scale);
}

// merged weight conversion: wq(*QSCALE), wk, wv -> wqkvb; wo -> wob
__global__ void cvt_weights(const float4* __restrict__ wq, const float4* __restrict__ wk,
                            const float4* __restrict__ wv, const float4* __restrict__ wo,
                            bf16* __restrict__ wqkvb, bf16* __restrict__ wob) {
    int i = blockIdx.x * blockDim.x + threadIdx.x;  // 0 .. 4*262144-1
    int mat = i >> 18, li = i & 262143;
    const float4* s = (mat == 0) ? wq : (mat == 1) ? wk : (mat == 2) ? wv : wo;
    bf16* d = (mat < 3) ? (wqkvb + (size_t)mat * 1024 * 1024) : wob;
    cvt_store(s[li], d, li << 2, (mat == 0) ? QSCALE : 1.f);
}

// swizzled LDS fragment read from linear [rows][64] bf16 tile (128B rows)
__device__ __forceinline__ bf16x8 fragswz(const bf16* base, int row, int kb) {
    return *reinterpret_cast<const bf16x8*>(
        reinterpret_cast<const char*>(base) + row * 128 + (kb ^ ((row & 7) << 4)));
}

// ---------------- m97-style GEMM: C[M][N] = A[M][K] @ B[N][K]^T + bias ----------------
template <int WN, int OUT_F32>
__global__ __launch_bounds__(256) void gemm_glds(
    const bf16* __restrict__ A, const bf16* __restrict__ Bm,
    const float* __restrict__ b0, const float* __restrict__ b1, const float* __restrict__ b2,
    float s0, void* __restrict__ Cv, int M, int N, int K)
{
    __shared__ __align__(16) bf16 As[128 * 64];
    __shared__ __align__(16) bf16 Bs[WN * 32 * 64];

    const int BN = WN * 32;
    const int nbn = N / BN;
    const int wrk = (blockIdx.x & 7) * ((int)gridDim.x >> 3) + (blockIdx.x >> 3);
    const int bm = wrk / nbn, bn = wrk % nbn;
    const int m0 = bm << 7, n0 = bn * BN;
    const int tid = threadIdx.x, lane = tid & 63, wid = tid >> 6;
    const int wr = wid >> 1, wc = wid & 1;
    const int lq = lane & 15, g = lane >> 4;

    f32x4 acc[4][WN];
    #pragma unroll
    for (int m = 0; m < 4; ++m)
        #pragma unroll
        for (int n = 0; n < WN; ++n)
            acc[m][n] = (f32x4){0.f, 0.f, 0.f, 0.f};

    for (int kt = 0; kt < K; kt += 64) {
        #pragma unroll
        for (int i = 0; i < 4; ++i) {
            int rb = wid * 32 + i * 8;
            gload16(&A[(size_t)(m0 + rb + (lane >> 3)) * K + kt + ((lane & 7) << 3)],
                    &As[rb * 64]);
        }
        #pragma unroll
        for (int i = 0; i < WN; ++i) {
            int rb = wid * (WN * 8) + i * 8;
            gload16(&Bm[(size_t)(n0 + rb + (lane >> 3)) * K + kt + ((lane & 7) << 3)],
                    &Bs[rb * 64]);
        }
        __syncthreads();

        bf16x8 af[4][2], bfr[WN][2];
        #pragma unroll
        for (int m = 0; m < 4; ++m)
            #pragma unroll
            for (int h2 = 0; h2 < 2; ++h2)
                af[m][h2] = fragswz(As, wr * 64 + m * 16 + lq, h2 * 64 + g * 16);
        #pragma unroll
        for (int n = 0; n < WN; ++n)
            #pragma unroll
            for (int h2 = 0; h2 < 2; ++h2)
                bfr[n][h2] = fragswz(Bs, wc * (WN * 16) + n * 16 + lq, h2 * 64 + g * 16);

        __builtin_amdgcn_s_setprio(1);
        #pragma unroll
        for (int m = 0; m < 4; ++m)
            #pragma unroll
            for (int n = 0; n < WN; ++n)
                #pragma unroll
                for (int h2 = 0; h2 < 2; ++h2)
                    acc[m][n] = __builtin_amdgcn_mfma_f32_16x16x32_bf16(
                        af[m][h2], bfr[n][h2], acc[m][n], 0, 0, 0);
        __builtin_amdgcn_s_setprio(0);
        __syncthreads();
    }

    const int seg = n0 >> 10;
    const float* bp = (seg == 0) ? b0 : ((seg == 1) ? b1 : b2);
    const float bsc = (seg == 0) ? s0 : 1.f;

    #pragma unroll
    for (int m = 0; m < 4; ++m) {
        #pragma unroll
        for (int n = 0; n < WN; ++n) {
            int rbase = m0 + wr * 64 + m * 16 + (g << 2);
            int col = n0 + wc * (WN * 16) + n * 16 + lq;
            float bv = bp[col - (seg << 10)] * bsc;
            #pragma unroll
            for (int r = 0; r < 4; ++r) {
                float v = acc[m][n][r] + bv;
                if (OUT_F32)
                    ((float*)Cv)[(size_t)(rbase + r) * N + col] = v;
                else
                    ((bf16*)Cv)[(size_t)(rbase + r) * N + col] = (bf16)v;
            }
        }
    }
}

// ---------------- fused decay-masked attention, split-K ----------------
// 1024 blocks = (h, qblk64, pair, khalf); 4 waves x 16 q-rows; 16 stages.
// No-max softmax -> partials are associative: O_unnorm/l atomicAdd'ed fp32.
// LDS = 40KB exactly (K/V/P at 64-stride + XOR chunk-swizzle) -> 4 blocks/CU.
struct KVRegs { bf16x8 k0, k1; u16x8 v0, v1; };

__device__ __forceinline__ void issue_loads(KVRegs& r, const bf16* qkv, int brow,
                                            int koff, int voff, int tid) {
    const int rK = tid >> 3, o8 = (tid & 7) << 3;
    r.k0 = *reinterpret_cast<const bf16x8*>(&qkv[(size_t)(brow + rK) * 3072 + koff + o8]);
    r.k1 = *reinterpret_cast<const bf16x8*>(&qkv[(size_t)(brow + rK + 32) * 3072 + koff + o8]);
    const int rV = rK << 1;
    r.v0 = *reinterpret_cast<const u16x8*>(&qkv[(size_t)(brow + rV) * 3072 + voff + o8]);
    r.v1 = *reinterpret_cast<const u16x8*>(&qkv[(size_t)(brow + rV + 1) * 3072 + voff + o8]);
}

__device__ __forceinline__ void write_stage(const KVRegs& r, bf16* Kb, bf16* Vb, int tid) {
    const int rK = tid >> 3, o = tid & 7;
    // K rows rK, rK+32 (b128, chunk-swizzled); (rK+32)&7 == rK&7
    char* kb = reinterpret_cast<char*>(Kb);
    int kx = (o << 4) ^ ((rK & 7) << 4);
    *reinterpret_cast<bf16x8*>(kb + rK * 128 + kx) = r.k0;
    *reinterpret_cast<bf16x8*>(kb + (rK + 32) * 128 + kx) = r.k1;
    // V^T rows d = o*8+j, col pair (2*rK, 2*rK+1) packed u32
    char* vb = reinterpret_cast<char*>(Vb);
    #pragma unroll
    for (int j = 0; j < 8; ++j) {
        int d = (o << 3) + j;
        int byteo = d * 128 + ((rK << 2) ^ ((d & 7) << 4));
        unsigned int w = (unsigned int)r.v0[j] | ((unsigned int)r.v1[j] << 16);
        *reinterpret_cast<unsigned int*>(vb + byteo) = w;
    }
}

__device__ __forceinline__ void compute_stage(
    const bf16* Kb, const bf16* Vb, bf16* Psw,
    const float4 (&mreg)[4], const bf16x8 (&aqb)[2],
    f32x4& lacc, f32x4 (&oacc)[4], int lane)
{
    const int lq = lane & 15, g = lane >> 4;
    f32x4 sacc[4];
    #pragma unroll
    for (int ct = 0; ct < 4; ++ct) sacc[ct] = (f32x4){0.f, 0.f, 0.f, 0.f};
    #pragma unroll
    for (int ct = 0; ct < 4; ++ct)
        #pragma unroll
        for (int h2 = 0; h2 < 2; ++h2)
            sacc[ct] = __builtin_amdgcn_mfma_f32_16x16x32_bf16(
                fragswz(Kb, ct * 16 + lq, h2 * 64 + g * 16), aqb[h2], sacc[ct], 0, 0, 0);

    // p = exp2(s * mask) (log2e pre-folded into q); accumulate row-sum; pack P
    char* pb8 = reinterpret_cast<char*>(Psw);
    const int px = (lq & 7) << 4;
    #pragma unroll
    for (int ct = 0; ct < 4; ++ct) {
        float p0 = __builtin_exp2f(sacc[ct][0] * mreg[ct].x);
        float p1 = __builtin_exp2f(sacc[ct][1] * mreg[ct].y);
        float p2 = __builtin_exp2f(sacc[ct][2] * mreg[ct].z);
        float p3 = __builtin_exp2f(sacc[ct][3] * mreg[ct].w);
        lacc[0] += p0; lacc[1] += p1; lacc[2] += p2; lacc[3] += p3;
        bf16x4 pbv;
        pbv[0] = (bf16)p0; pbv[1] = (bf16)p1; pbv[2] = (bf16)p2; pbv[3] = (bf16)p3;
        *reinterpret_cast<bf16x4*>(pb8 + lq * 128 + (((ct << 5) + (g << 3)) ^ px)) = pbv;
    }

    // O^T += mfma(V^T rows d, P rows q)
    const char* vb = reinterpret_cast<const char*>(Vb);
    #pragma unroll
    for (int ot = 0; ot < 4; ++ot) {
        #pragma unroll
        for (int h2 = 0; h2 < 2; ++h2) {
            int d = ot * 16 + lq;
            int kb = h2 * 64 + g * 16;
            bf16x8 vf = *reinterpret_cast<const bf16x8*>(vb + d * 128 + (kb ^ ((d & 7) << 4)));
            bf16x8 pf = *reinterpret_cast<const bf16x8*>(pb8 + lq * 128 + (kb ^ px));
            oacc[ot] = __builtin_amdgcn_mfma_f32_16x16x32_bf16(vf, pf, oacc[ot], 0, 0, 0);
        }
    }
}

__global__ __launch_bounds__(256, 4) void attn_kernel(
    const bf16* __restrict__ qkv, const float* __restrict__ mask,
    float* __restrict__ Osum, float* __restrict__ lpart)
{
    __shared__ __align__(16) bf16 Kbuf[2][64 * 64];
    __shared__ __align__(16) bf16 Vbuf[2][64 * 64];
    __shared__ __align__(16) bf16 Ps[4][16 * 64];

    // bid = xcd + 8*slot; slot: bp | khalf<<1 | pg_local<<2 (siblings same XCD)
    const int bid = blockIdx.x;
    const int xcd = bid & 7, slot = bid >> 3;
    const int bp = slot & 1;
    const int khalf = (slot >> 1) & 1;
    const int pg = xcd * 32 + (slot >> 2);
    const int h = pg >> 4, qblk = pg & 15;

    const int tid = threadIdx.x, lane = tid & 63, wid = tid >> 6;
    const int lq = lane & 15, g = lane >> 4;
    const int q = (qblk << 6) + wid * 16 + lq;
    const int k0 = khalf << 9;
    const int koff = 1024 + h * HEADDIM, voff = 2048 + h * HEADDIM, qoff = h * HEADDIM;
    const float* mh = mask + (size_t)h * SEQ * SEQ + (size_t)q * SEQ + k0;

    // Q fragments (pre-scaled by QSCALE via wq)
    bf16x8 aq[2][2];
    #pragma unroll
    for (int bi = 0; bi < 2; ++bi)
        #pragma unroll
        for (int h2 = 0; h2 < 2; ++h2)
            aq[bi][h2] = *reinterpret_cast<const bf16x8*>(
                &qkv[(size_t)((bp * 2 + bi) * SEQ + q) * 3072 + qoff + h2 * 32 + g * 8]);

    f32x4 lacc[2] = {};
    f32x4 oacc[2][4] = {};

    // prologue
    KVRegs s0, s1;
    issue_loads(s0, qkv, (bp * 2 + 0) * SEQ + k0, koff, voff, tid);
    issue_loads(s1, qkv, (bp * 2 + 1) * SEQ + k0, koff, voff, tid);
    float4 mregA[4], mregB[4];
    #pragma unroll
    for (int ct = 0; ct < 4; ++ct) {
        mregA[ct] = *reinterpret_cast<const float4*>(&mh[ct * 16 + (g << 2)]);
        mregB[ct] = *reinterpret_cast<const float4*>(&mh[64 + ct * 16 + (g << 2)]);
    }
    write_stage(s0, Kbuf[0], Vbuf[0], tid);
    __syncthreads();

    for (int t = 0; t < 8; ++t) {
        // --- stage (t, bi=0) from buf0 ---
        if (t < 7) issue_loads(s0, qkv, (bp * 2 + 0) * SEQ + k0 + (t + 1) * 64, koff, voff, tid);
        compute_stage(Kbuf[0], Vbuf[0], Ps[wid], mregA, aq[0], lacc[0], oacc[0], lane);
        write_stage(s1, Kbuf[1], Vbuf[1], tid);
        __syncthreads();

        // --- stage (t, bi=1) from buf1 ---
        if (t < 7) issue_loads(s1, qkv, (bp * 2 + 1) * SEQ + k0 + (t + 1) * 64, koff, voff, tid);
        compute_stage(Kbuf[1], Vbuf[1], Ps[wid], mregA, aq[1], lacc[1], oacc[1], lane);
        #pragma unroll
        for (int ct = 0; ct < 4; ++ct) mregA[ct] = mregB[ct];
        if (t < 6)
            #pragma unroll
            for (int ct = 0; ct < 4; ++ct)
                mregB[ct] = *reinterpret_cast<const float4*>(&mh[(t + 2) * 64 + ct * 16 + (g << 2)]);
        if (t < 7) write_stage(s0, Kbuf[0], Vbuf[0], tid);
        __syncthreads();
    }

    // epilogue: atomic-accumulate unnormalized O^T and l (2 commutative fp32
    // adds per address -> deterministic)
    #pragma unroll
    for (int bi = 0; bi < 2; ++bi) {
        int row = (bp * 2 + bi) * SEQ + q;
        float lsum = lacc[bi][0] + lacc[bi][1] + lacc[bi][2] + lacc[bi][3];
        lsum += __shfl_xor(lsum, 16, 64);
        lsum += __shfl_xor(lsum, 32, 64);
        if (g == 0) atomicAdd(&lpart[row * 16 + h], lsum);
        #pragma unroll
        for (int ot = 0; ot < 4; ++ot) {
            float* dst = &Osum[(size_t)row * DIMSZ + h * HEADDIM + ot * 16 + (g << 2)];
            #pragma unroll
            for (int r = 0; r < 4; ++r)
                atomicAdd(dst + r, oacc[bi][ot][r]);
        }
    }
}

// normalize partials -> bf16 chunk-swizzled aob
__global__ __launch_bounds__(256) void combine_kernel(
    const float* __restrict__ Osum, const float* __restrict__ lpart,
    bf16* __restrict__ aob)
{
    int i = blockIdx.x * blockDim.x + threadIdx.x;   // 0..2^20-1, 4 elems each
    int row = i >> 8, c4 = (i & 255) << 2;
    float4 o = *reinterpret_cast<const float4*>(&Osum[(size_t)row * 1024 + c4]);
    float inv = 1.f / lpart[row * 16 + (c4 >> 6)];
    int col2 = (c4 & ~63) | (c4 & 7) | (((((c4 >> 3) & 7) ^ (row & 7))) << 3);
    bf16x4 ob;
    ob[0] = (bf16)(o.x * inv); ob[1] = (bf16)(o.y * inv);
    ob[2] = (bf16)(o.z * inv); ob[3] = (bf16)(o.w * inv);
    *reinterpret_cast<bf16x4*>(&aob[(size_t)row * 1024 + col2]) = ob;
}

extern "C" void kernel_launch(void* const* d_in, const int* in_sizes, int n_in,
                              void* d_out, int out_size, void* d_ws, size_t ws_size,
                              hipStream_t stream) {
    const float* x    = (const float*)d_in[0];
    const float* mask = (const float*)d_in[1];
    const float* wq   = (const float*)d_in[2];
    const float* bq   = (const float*)d_in[3];
    const float* wk   = (const float*)d_in[4];
    const float* bk   = (const float*)d_in[5];
    const float* wv   = (const float*)d_in[6];
    const float* bv   = (const float*)d_in[7];
    const float* wo   = (const float*)d_in[8];
    const float* bo   = (const float*)d_in[9];
    float* out = (float*)d_out;

    const size_t MTOK = (size_t)BATCH * SEQ;             // 4096
    char* ws = (char*)d_ws;
    bf16* xb    = (bf16*)ws; ws += MTOK * DIMSZ * 2;                 // 8 MB
    bf16* wqkvb = (bf16*)ws; ws += (size_t)3 * DIMSZ * DIMSZ * 2;    // 6 MB
    bf16* wob   = (bf16*)ws; ws += (size_t)DIMSZ * DIMSZ * 2;        // 2 MB
    bf16* qkv   = (bf16*)ws; ws += MTOK * 3 * DIMSZ * 2;             // 24 MB
    bf16* aob   = (bf16*)ws; ws += MTOK * DIMSZ * 2;                 // 8 MB
    float* lpart = (float*)ws; ws += MTOK * NHEADS * 4;              // 256 KB -> 48.25 MB

    // zero the partial accumulators (d_out doubles as fp32 O-partial scratch)
    hipMemsetAsync(d_out, 0, MTOK * DIMSZ * 4, stream);
    hipMemsetAsync(lpart, 0, MTOK * NHEADS * 4, stream);

    int n4x = (int)(MTOK * DIMSZ / 4);
    cvt_swz<<<(n4x + 255) / 256, 256, 0, stream>>>((const float4*)x, xb, n4x, 1.f);
    cvt_weights<<<(4 * 262144) / 256, 256, 0, stream>>>(
        (const float4*)wq, (const float4*)wk, (const float4*)wv, (const float4*)wo,
        wqkvb, wob);

    // fused QKV projection: [4096,1024] @ [3072,1024]^T -> [4096,3072]
    gemm_glds<4, 0><<<(MTOK / 128) * (3 * DIMSZ / 128), 256, 0, stream>>>(
        xb, wqkvb, bq, bk, bv, QSCALE, qkv, (int)MTOK, 3 * DIMSZ, DIMSZ);

    // fused attention, split-K partials into d_out (fp32) + lpart
    attn_kernel<<<1024, 256, 0, stream>>>(qkv, mask, (float*)d_out, lpart);

    // normalize -> aob (bf16, chunk-swizzled)
    combine_kernel<<<4096, 256, 0, stream>>>((const float*)d_out, lpart, aob);

    // output projection: [4096,1024] @ [1024,1024]^T -> [4096,1024] fp32
    gemm_glds<2, 1><<<(MTOK / 128) * (DIMSZ / 64), 256, 0, stream>>>(
        aob, wob, bo, bo, bo, 1.f, out, (int)MTOK, DIMSZ, DIMSZ);
}

// Round 7
// 268.655 us; speedup vs baseline: 1.2837x; 1.2837x over previous
//
#include <hip/hip_runtime.h>
#include <hip/hip_bf16.h>
#include <math.h>

typedef __bf16 bf16;
typedef __bf16 bf16x8 __attribute__((ext_vector_type(8)));
typedef __bf16 bf16x4 __attribute__((ext_vector_type(4)));
typedef float f32x4 __attribute__((ext_vector_type(4)));
typedef unsigned short u16;
typedef u16 u16x8 __attribute__((ext_vector_type(8)));

#define SEQ 1024
#define DIMSZ 1024
#define NHEADS 16
#define HEADDIM 64
#define BATCH 4
#define MTOK (BATCH * SEQ)

// q-scale: 1/sqrt(64) * log2(e)  (log2e folded so softmax uses raw exp2)
#define QSCALE 0.180336880f

// ---------------- async global->LDS (16B per lane, linear dest) ----------------
typedef __attribute__((address_space(1))) const unsigned char gas_u8;
typedef __attribute__((address_space(3))) unsigned char las_u8;
__device__ __forceinline__ void gload16(const void* g, void* l) {
    __builtin_amdgcn_global_load_lds((const gas_u8*)g, (las_u8*)l, 16, 0, 0);
}

// ---------------- fp32 -> bf16 conversion with baked chunk-swizzle ----------------
// dst element (row, col) stored at chunk ^= (row&7) within each 64-col group
__device__ __forceinline__ void cvt_store(const float4 v, bf16* dst, int e0, float scale) {
    int row = e0 >> 10, col = e0 & 1023;
    int col2 = (col & ~63) | (col & 7) | (((((col >> 3) & 7) ^ (row & 7))) << 3);
    bf16x4 o;
    o[0] = (bf16)(v.x * scale);
    o[1] = (bf16)(v.y * scale);
    o[2] = (bf16)(v.z * scale);
    o[3] = (bf16)(v.w * scale);
    *reinterpret_cast<bf16x4*>(&dst[(size_t)row * 1024 + col2]) = o;
}

__global__ void cvt_swz(const float4* __restrict__ src, bf16* __restrict__ dst,
                        int n4, float scale) {
    int i = blockIdx.x * blockDim.x + threadIdx.x;
    if (i >= n4) return;
    cvt_store(src[i], dst, i << 2, scale);
}

// merged weight conversion: wq(*QSCALE), wk, wv -> wqkvb; wo -> wob
__global__ void cvt_weights(const float4* __restrict__ wq, const float4* __restrict__ wk,
                            const float4* __restrict__ wv, const float4* __restrict__ wo,
                            bf16* __restrict__ wqkvb, bf16* __restrict__ wob) {
    int i = blockIdx.x * blockDim.x + threadIdx.x;  // 0 .. 4*262144-1
    int mat = i >> 18, li = i & 262143;
    const float4* s = (mat == 0) ? wq : (mat == 1) ? wk : (mat == 2) ? wv : wo;
    bf16* d = (mat < 3) ? (wqkvb + (size_t)mat * 1024 * 1024) : wob;
    cvt_store(s[li], d, li << 2, (mat == 0) ? QSCALE : 1.f);
}

// swizzled LDS fragment read from linear [rows][64] bf16 tile (128B rows)
__device__ __forceinline__ bf16x8 fragswz(const bf16* base, int row, int kb) {
    return *reinterpret_cast<const bf16x8*>(
        reinterpret_cast<const char*>(base) + row * 128 + (kb ^ ((row & 7) << 4)));
}

// ---------------- m97-style GEMM: C[M][N] = A[M][K] @ B[N][K]^T + bias ----------------
template <int WN, int OUT_F32>
__global__ __launch_bounds__(256) void gemm_glds(
    const bf16* __restrict__ A, const bf16* __restrict__ Bm,
    const float* __restrict__ b0, const float* __restrict__ b1, const float* __restrict__ b2,
    float s0, void* __restrict__ Cv, int M, int N, int K)
{
    __shared__ __align__(16) bf16 As[128 * 64];
    __shared__ __align__(16) bf16 Bs[WN * 32 * 64];

    const int BN = WN * 32;
    const int nbn = N / BN;
    const int wrk = (blockIdx.x & 7) * ((int)gridDim.x >> 3) + (blockIdx.x >> 3);
    const int bm = wrk / nbn, bn = wrk % nbn;
    const int m0 = bm << 7, n0 = bn * BN;
    const int tid = threadIdx.x, lane = tid & 63, wid = tid >> 6;
    const int wr = wid >> 1, wc = wid & 1;
    const int lq = lane & 15, g = lane >> 4;

    f32x4 acc[4][WN];
    #pragma unroll
    for (int m = 0; m < 4; ++m)
        #pragma unroll
        for (int n = 0; n < WN; ++n)
            acc[m][n] = (f32x4){0.f, 0.f, 0.f, 0.f};

    for (int kt = 0; kt < K; kt += 64) {
        #pragma unroll
        for (int i = 0; i < 4; ++i) {
            int rb = wid * 32 + i * 8;
            gload16(&A[(size_t)(m0 + rb + (lane >> 3)) * K + kt + ((lane & 7) << 3)],
                    &As[rb * 64]);
        }
        #pragma unroll
        for (int i = 0; i < WN; ++i) {
            int rb = wid * (WN * 8) + i * 8;
            gload16(&Bm[(size_t)(n0 + rb + (lane >> 3)) * K + kt + ((lane & 7) << 3)],
                    &Bs[rb * 64]);
        }
        __syncthreads();

        bf16x8 af[4][2], bfr[WN][2];
        #pragma unroll
        for (int m = 0; m < 4; ++m)
            #pragma unroll
            for (int h2 = 0; h2 < 2; ++h2)
                af[m][h2] = fragswz(As, wr * 64 + m * 16 + lq, h2 * 64 + g * 16);
        #pragma unroll
        for (int n = 0; n < WN; ++n)
            #pragma unroll
            for (int h2 = 0; h2 < 2; ++h2)
                bfr[n][h2] = fragswz(Bs, wc * (WN * 16) + n * 16 + lq, h2 * 64 + g * 16);

        #pragma unroll
        for (int m = 0; m < 4; ++m)
            #pragma unroll
            for (int n = 0; n < WN; ++n)
                #pragma unroll
                for (int h2 = 0; h2 < 2; ++h2)
                    acc[m][n] = __builtin_amdgcn_mfma_f32_16x16x32_bf16(
                        af[m][h2], bfr[n][h2], acc[m][n], 0, 0, 0);
        __syncthreads();
    }

    const int seg = n0 >> 10;
    const float* bp = (seg == 0) ? b0 : ((seg == 1) ? b1 : b2);
    const float bsc = (seg == 0) ? s0 : 1.f;

    #pragma unroll
    for (int m = 0; m < 4; ++m) {
        #pragma unroll
        for (int n = 0; n < WN; ++n) {
            int rbase = m0 + wr * 64 + m * 16 + (g << 2);
            int col = n0 + wc * (WN * 16) + n * 16 + lq;
            float bv = bp[col - (seg << 10)] * bsc;
            #pragma unroll
            for (int r = 0; r < 4; ++r) {
                float v = acc[m][n][r] + bv;
                if (OUT_F32)
                    ((float*)Cv)[(size_t)(rbase + r) * N + col] = v;
                else
                    ((bf16*)Cv)[(size_t)(rbase + r) * N + col] = (bf16)v;
            }
        }
    }
}

// ---------------- fused decay-masked attention, two-pass split-K ----------------
// 1024 blocks = (h, qblk64, pair, khalf); 4 waves x 16 q-rows; 16 stages.
// No-max softmax -> partials additive. Each khalf writes its own partial O
// (unnormalized bf16) + partial l (fp32) with plain stores (NO atomics).
// LDS = 40KB exactly -> 4 blocks/CU at grid 1024.
struct KVRegs { bf16x8 k0, k1; u16x8 v0, v1; };

__device__ __forceinline__ void issue_loads(KVRegs& r, const bf16* qkv, int brow,
                                            int koff, int voff, int tid) {
    const int rK = tid >> 3, o8 = (tid & 7) << 3;
    r.k0 = *reinterpret_cast<const bf16x8*>(&qkv[(size_t)(brow + rK) * 3072 + koff + o8]);
    r.k1 = *reinterpret_cast<const bf16x8*>(&qkv[(size_t)(brow + rK + 32) * 3072 + koff + o8]);
    const int rV = rK << 1;
    r.v0 = *reinterpret_cast<const u16x8*>(&qkv[(size_t)(brow + rV) * 3072 + voff + o8]);
    r.v1 = *reinterpret_cast<const u16x8*>(&qkv[(size_t)(brow + rV + 1) * 3072 + voff + o8]);
}

__device__ __forceinline__ void write_stage(const KVRegs& r, bf16* Kb, bf16* Vb, int tid) {
    const int rK = tid >> 3, o = tid & 7;
    char* kb = reinterpret_cast<char*>(Kb);
    int kx = (o << 4) ^ ((rK & 7) << 4);
    *reinterpret_cast<bf16x8*>(kb + rK * 128 + kx) = r.k0;
    *reinterpret_cast<bf16x8*>(kb + (rK + 32) * 128 + kx) = r.k1;
    char* vb = reinterpret_cast<char*>(Vb);
    #pragma unroll
    for (int j = 0; j < 8; ++j) {
        int d = (o << 3) + j;
        int byteo = d * 128 + ((rK << 2) ^ ((d & 7) << 4));
        unsigned int w = (unsigned int)r.v0[j] | ((unsigned int)r.v1[j] << 16);
        *reinterpret_cast<unsigned int*>(vb + byteo) = w;
    }
}

__device__ __forceinline__ void compute_stage(
    const bf16* Kb, const bf16* Vb, bf16* Psw,
    const float4 (&mreg)[4], const bf16x8 (&aqb)[2],
    f32x4& lacc, f32x4 (&oacc)[4], int lane)
{
    const int lq = lane & 15, g = lane >> 4;
    f32x4 sacc[4];
    #pragma unroll
    for (int ct = 0; ct < 4; ++ct) sacc[ct] = (f32x4){0.f, 0.f, 0.f, 0.f};
    #pragma unroll
    for (int ct = 0; ct < 4; ++ct)
        #pragma unroll
        for (int h2 = 0; h2 < 2; ++h2)
            sacc[ct] = __builtin_amdgcn_mfma_f32_16x16x32_bf16(
                fragswz(Kb, ct * 16 + lq, h2 * 64 + g * 16), aqb[h2], sacc[ct], 0, 0, 0);

    // p = exp2(s * mask) (log2e pre-folded into q); accumulate row-sum; pack P
    char* pb8 = reinterpret_cast<char*>(Psw);
    const int px = (lq & 7) << 4;
    #pragma unroll
    for (int ct = 0; ct < 4; ++ct) {
        float p0 = __builtin_exp2f(sacc[ct][0] * mreg[ct].x);
        float p1 = __builtin_exp2f(sacc[ct][1] * mreg[ct].y);
        float p2 = __builtin_exp2f(sacc[ct][2] * mreg[ct].z);
        float p3 = __builtin_exp2f(sacc[ct][3] * mreg[ct].w);
        lacc[0] += p0; lacc[1] += p1; lacc[2] += p2; lacc[3] += p3;
        bf16x4 pbv;
        pbv[0] = (bf16)p0; pbv[1] = (bf16)p1; pbv[2] = (bf16)p2; pbv[3] = (bf16)p3;
        *reinterpret_cast<bf16x4*>(pb8 + lq * 128 + (((ct << 5) + (g << 3)) ^ px)) = pbv;
    }

    // O^T += mfma(V^T rows d, P rows q)
    const char* vb = reinterpret_cast<const char*>(Vb);
    #pragma unroll
    for (int ot = 0; ot < 4; ++ot) {
        #pragma unroll
        for (int h2 = 0; h2 < 2; ++h2) {
            int d = ot * 16 + lq;
            int kb = h2 * 64 + g * 16;
            bf16x8 vf = *reinterpret_cast<const bf16x8*>(vb + d * 128 + (kb ^ ((d & 7) << 4)));
            bf16x8 pf = *reinterpret_cast<const bf16x8*>(pb8 + lq * 128 + (kb ^ px));
            oacc[ot] = __builtin_amdgcn_mfma_f32_16x16x32_bf16(vf, pf, oacc[ot], 0, 0, 0);
        }
    }
}

__global__ __launch_bounds__(256, 4) void attn_kernel(
    const bf16* __restrict__ qkv, const float* __restrict__ mask,
    bf16* __restrict__ Opart, float* __restrict__ lpart)
{
    __shared__ __align__(16) bf16 Kbuf[2][64 * 64];
    __shared__ __align__(16) bf16 Vbuf[2][64 * 64];
    __shared__ __align__(16) bf16 Ps[4][16 * 64];

    // bid = xcd + 8*slot; slot: bp | khalf<<1 | pg_local<<2 (siblings same XCD)
    const int bid = blockIdx.x;
    const int xcd = bid & 7, slot = bid >> 3;
    const int bp = slot & 1;
    const int khalf = (slot >> 1) & 1;
    const int pg = xcd * 32 + (slot >> 2);
    const int h = pg >> 4, qblk = pg & 15;

    const int tid = threadIdx.x, lane = tid & 63, wid = tid >> 6;
    const int lq = lane & 15, g = lane >> 4;
    const int q = (qblk << 6) + wid * 16 + lq;
    const int k0 = khalf << 9;
    const int koff = 1024 + h * HEADDIM, voff = 2048 + h * HEADDIM, qoff = h * HEADDIM;
    const float* mh = mask + (size_t)h * SEQ * SEQ + (size_t)q * SEQ + k0;

    // Q fragments (pre-scaled by QSCALE via wq)
    bf16x8 aq[2][2];
    #pragma unroll
    for (int bi = 0; bi < 2; ++bi)
        #pragma unroll
        for (int h2 = 0; h2 < 2; ++h2)
            aq[bi][h2] = *reinterpret_cast<const bf16x8*>(
                &qkv[(size_t)((bp * 2 + bi) * SEQ + q) * 3072 + qoff + h2 * 32 + g * 8]);

    f32x4 lacc[2] = {};
    f32x4 oacc[2][4] = {};

    // prologue
    KVRegs s0, s1;
    issue_loads(s0, qkv, (bp * 2 + 0) * SEQ + k0, koff, voff, tid);
    issue_loads(s1, qkv, (bp * 2 + 1) * SEQ + k0, koff, voff, tid);
    float4 mregA[4], mregB[4];
    #pragma unroll
    for (int ct = 0; ct < 4; ++ct) {
        mregA[ct] = *reinterpret_cast<const float4*>(&mh[ct * 16 + (g << 2)]);
        mregB[ct] = *reinterpret_cast<const float4*>(&mh[64 + ct * 16 + (g << 2)]);
    }
    write_stage(s0, Kbuf[0], Vbuf[0], tid);
    __syncthreads();

    for (int t = 0; t < 8; ++t) {
        // --- stage (t, bi=0) from buf0 ---
        if (t < 7) issue_loads(s0, qkv, (bp * 2 + 0) * SEQ + k0 + (t + 1) * 64, koff, voff, tid);
        compute_stage(Kbuf[0], Vbuf[0], Ps[wid], mregA, aq[0], lacc[0], oacc[0], lane);
        write_stage(s1, Kbuf[1], Vbuf[1], tid);
        __syncthreads();

        // --- stage (t, bi=1) from buf1 ---
        if (t < 7) issue_loads(s1, qkv, (bp * 2 + 1) * SEQ + k0 + (t + 1) * 64, koff, voff, tid);
        compute_stage(Kbuf[1], Vbuf[1], Ps[wid], mregA, aq[1], lacc[1], oacc[1], lane);
        #pragma unroll
        for (int ct = 0; ct < 4; ++ct) mregA[ct] = mregB[ct];
        if (t < 6)
            #pragma unroll
            for (int ct = 0; ct < 4; ++ct)
                mregB[ct] = *reinterpret_cast<const float4*>(&mh[(t + 2) * 64 + ct * 16 + (g << 2)]);
        if (t < 7) write_stage(s0, Kbuf[0], Vbuf[0], tid);
        __syncthreads();
    }

    // epilogue: plain coalesced stores of partials (deterministic, no atomics)
    bf16* op = Opart + (size_t)khalf * MTOK * DIMSZ;
    float* lp = lpart + khalf * MTOK * NHEADS;
    #pragma unroll
    for (int bi = 0; bi < 2; ++bi) {
        int row = (bp * 2 + bi) * SEQ + q;
        float lsum = lacc[bi][0] + lacc[bi][1] + lacc[bi][2] + lacc[bi][3];
        lsum += __shfl_xor(lsum, 16, 64);
        lsum += __shfl_xor(lsum, 32, 64);
        if (g == 0) lp[row * 16 + h] = lsum;
        #pragma unroll
        for (int ot = 0; ot < 4; ++ot) {
            bf16x4 o;
            o[0] = (bf16)oacc[bi][ot][0];
            o[1] = (bf16)oacc[bi][ot][1];
            o[2] = (bf16)oacc[bi][ot][2];
            o[3] = (bf16)oacc[bi][ot][3];
            *reinterpret_cast<bf16x4*>(
                &op[(size_t)row * DIMSZ + h * HEADDIM + ot * 16 + (g << 2)]) = o;
        }
    }
}

// combine: (O0 + O1) / (l0 + l1) -> bf16 chunk-swizzled aob
__global__ __launch_bounds__(256) void combine_kernel(
    const bf16* __restrict__ Opart, const float* __restrict__ lpart,
    bf16* __restrict__ aob)
{
    int i = blockIdx.x * blockDim.x + threadIdx.x;   // 0..2^20-1, 4 elems each
    int row = i >> 8, c4 = (i & 255) << 2;
    bf16x4 a = *reinterpret_cast<const bf16x4*>(&Opart[(size_t)row * 1024 + c4]);
    bf16x4 b = *reinterpret_cast<const bf16x4*>(
        &Opart[(size_t)(MTOK + row) * 1024 + c4]);
    int h = c4 >> 6;
    float inv = 1.f / (lpart[row * 16 + h] + lpart[MTOK * 16 + row * 16 + h]);
    int col2 = (c4 & ~63) | (c4 & 7) | (((((c4 >> 3) & 7) ^ (row & 7))) << 3);
    bf16x4 ob;
    ob[0] = (bf16)(((float)a[0] + (float)b[0]) * inv);
    ob[1] = (bf16)(((float)a[1] + (float)b[1]) * inv);
    ob[2] = (bf16)(((float)a[2] + (float)b[2]) * inv);
    ob[3] = (bf16)(((float)a[3] + (float)b[3]) * inv);
    *reinterpret_cast<bf16x4*>(&aob[(size_t)row * 1024 + col2]) = ob;
}

extern "C" void kernel_launch(void* const* d_in, const int* in_sizes, int n_in,
                              void* d_out, int out_size, void* d_ws, size_t ws_size,
                              hipStream_t stream) {
    const float* x    = (const float*)d_in[0];
    const float* mask = (const float*)d_in[1];
    const float* wq   = (const float*)d_in[2];
    const float* bq   = (const float*)d_in[3];
    const float* wk   = (const float*)d_in[4];
    const float* bk   = (const float*)d_in[5];
    const float* wv   = (const float*)d_in[6];
    const float* bv   = (const float*)d_in[7];
    const float* wo   = (const float*)d_in[8];
    const float* bo   = (const float*)d_in[9];
    float* out = (float*)d_out;

    char* ws = (char*)d_ws;
    bf16* xb    = (bf16*)ws; ws += (size_t)MTOK * DIMSZ * 2;         // 8 MB
    bf16* wqkvb = (bf16*)ws; ws += (size_t)3 * DIMSZ * DIMSZ * 2;    // 6 MB
    bf16* wob   = (bf16*)ws; ws += (size_t)DIMSZ * DIMSZ * 2;        // 2 MB
    bf16* qkv   = (bf16*)ws; ws += (size_t)MTOK * 3 * DIMSZ * 2;     // 24 MB
    bf16* aob   = (bf16*)ws; ws += (size_t)MTOK * DIMSZ * 2;         // 8 MB
    float* lpart = (float*)ws; ws += (size_t)2 * MTOK * NHEADS * 4;  // 512 KB -> 48.5 MB
    // d_out (16.8 MB fp32) doubles as the two bf16 partial-O buffers
    bf16* Opart = (bf16*)d_out;

    int n4x = (int)((size_t)MTOK * DIMSZ / 4);
    cvt_swz<<<(n4x + 255) / 256, 256, 0, stream>>>((const float4*)x, xb, n4x, 1.f);
    cvt_weights<<<(4 * 262144) / 256, 256, 0, stream>>>(
        (const float4*)wq, (const float4*)wk, (const float4*)wv, (const float4*)wo,
        wqkvb, wob);

    // fused QKV projection: [4096,1024] @ [3072,1024]^T -> [4096,3072]
    gemm_glds<4, 0><<<(MTOK / 128) * (3 * DIMSZ / 128), 256, 0, stream>>>(
        xb, wqkvb, bq, bk, bv, QSCALE, qkv, MTOK, 3 * DIMSZ, DIMSZ);

    // fused attention, two-pass split-K partials (bf16 O into d_out, fp32 l)
    attn_kernel<<<1024, 256, 0, stream>>>(qkv, mask, Opart, lpart);

    // combine halves, normalize -> aob (bf16, chunk-swizzled)
    combine_kernel<<<4096, 256, 0, stream>>>(Opart, lpart, aob);

    // output projection: [4096,1024] @ [1024,1024]^T -> [4096,1024] fp32
    gemm_glds<2, 1><<<(MTOK / 128) * (DIMSZ / 64), 256, 0, stream>>>(
        aob, wob, bo, bo, bo, 1.f, out, MTOK, DIMSZ, DIMSZ);
}

// Round 8
// 138.635 us; speedup vs baseline: 2.4876x; 1.9379x over previous
//
#include <hip/hip_runtime.h>
#include <hip/hip_bf16.h>
#include <math.h>

typedef __bf16 bf16;
typedef __bf16 bf16x8 __attribute__((ext_vector_type(8)));
typedef __bf16 bf16x4 __attribute__((ext_vector_type(4)));
typedef float f32x4 __attribute__((ext_vector_type(4)));
typedef unsigned short u16;
typedef u16 u16x8 __attribute__((ext_vector_type(8)));

#define SEQ 1024
#define DIMSZ 1024
#define NHEADS 16
#define HEADDIM 64
#define BATCH 4
#define MTOK (BATCH * SEQ)
#define KT 128   // attn k-tile

// q-scale: 1/sqrt(64) * log2(e)  (log2e folded so softmax uses raw exp2)
#define QSCALE 0.180336880f

// ---------------- async global->LDS (16B per lane, linear dest) ----------------
typedef __attribute__((address_space(1))) const unsigned char gas_u8;
typedef __attribute__((address_space(3))) unsigned char las_u8;
__device__ __forceinline__ void gload16(const void* g, void* l) {
    __builtin_amdgcn_global_load_lds((const gas_u8*)g, (las_u8*)l, 16, 0, 0);
}

// ---------------- fp32 -> bf16 conversion with baked chunk-swizzle ----------------
// dst element (row, col) stored at chunk ^= (row&7) within each 64-col group
__device__ __forceinline__ void cvt_store(const float4 v, bf16* dst, int e0, float scale) {
    int row = e0 >> 10, col = e0 & 1023;
    int col2 = (col & ~63) | (col & 7) | (((((col >> 3) & 7) ^ (row & 7))) << 3);
    bf16x4 o;
    o[0] = (bf16)(v.x * scale);
    o[1] = (bf16)(v.y * scale);
    o[2] = (bf16)(v.z * scale);
    o[3] = (bf16)(v.w * scale);
    *reinterpret_cast<bf16x4*>(&dst[(size_t)row * 1024 + col2]) = o;
}

__global__ void cvt_swz(const float4* __restrict__ src, bf16* __restrict__ dst,
                        int n4, float scale) {
    int i = blockIdx.x * blockDim.x + threadIdx.x;
    if (i >= n4) return;
    cvt_store(src[i], dst, i << 2, scale);
}

// merged weight conversion: wq(*QSCALE), wk, wv -> wqkvb; wo -> wob
__global__ void cvt_weights(const float4* __restrict__ wq, const float4* __restrict__ wk,
                            const float4* __restrict__ wv, const float4* __restrict__ wo,
                            bf16* __restrict__ wqkvb, bf16* __restrict__ wob) {
    int i = blockIdx.x * blockDim.x + threadIdx.x;  // 0 .. 4*262144-1
    int mat = i >> 18, li = i & 262143;
    const float4* s = (mat == 0) ? wq : (mat == 1) ? wk : (mat == 2) ? wv : wo;
    bf16* d = (mat < 3) ? (wqkvb + (size_t)mat * 1024 * 1024) : wob;
    cvt_store(s[li], d, li << 2, (mat == 0) ? QSCALE : 1.f);
}

// swizzled LDS fragment read from linear [rows][64] bf16 tile (128B rows)
__device__ __forceinline__ bf16x8 fragswz(const bf16* base, int row, int kb) {
    return *reinterpret_cast<const bf16x8*>(
        reinterpret_cast<const char*>(base) + row * 128 + (kb ^ ((row & 7) << 4)));
}

// ---------------- m97-style GEMM: C[M][N] = A[M][K] @ B[N][K]^T + bias ----------------
// A, B stored pre-swizzled. bf16 output ALSO stored chunk-swizzled by row.
template <int WN, int OUT_F32>
__global__ __launch_bounds__(256) void gemm_glds(
    const bf16* __restrict__ A, const bf16* __restrict__ Bm,
    const float* __restrict__ b0, const float* __restrict__ b1, const float* __restrict__ b2,
    float s0, void* __restrict__ Cv, int M, int N, int K)
{
    __shared__ __align__(16) bf16 As[128 * 64];
    __shared__ __align__(16) bf16 Bs[WN * 32 * 64];

    const int BN = WN * 32;
    const int nbn = N / BN;
    const int wrk = (blockIdx.x & 7) * ((int)gridDim.x >> 3) + (blockIdx.x >> 3);
    const int bm = wrk / nbn, bn = wrk % nbn;
    const int m0 = bm << 7, n0 = bn * BN;
    const int tid = threadIdx.x, lane = tid & 63, wid = tid >> 6;
    const int wr = wid >> 1, wc = wid & 1;
    const int lq = lane & 15, g = lane >> 4;

    f32x4 acc[4][WN];
    #pragma unroll
    for (int m = 0; m < 4; ++m)
        #pragma unroll
        for (int n = 0; n < WN; ++n)
            acc[m][n] = (f32x4){0.f, 0.f, 0.f, 0.f};

    for (int kt = 0; kt < K; kt += 64) {
        #pragma unroll
        for (int i = 0; i < 4; ++i) {
            int rb = wid * 32 + i * 8;
            gload16(&A[(size_t)(m0 + rb + (lane >> 3)) * K + kt + ((lane & 7) << 3)],
                    &As[rb * 64]);
        }
        #pragma unroll
        for (int i = 0; i < WN; ++i) {
            int rb = wid * (WN * 8) + i * 8;
            gload16(&Bm[(size_t)(n0 + rb + (lane >> 3)) * K + kt + ((lane & 7) << 3)],
                    &Bs[rb * 64]);
        }
        __syncthreads();

        bf16x8 af[4][2], bfr[WN][2];
        #pragma unroll
        for (int m = 0; m < 4; ++m)
            #pragma unroll
            for (int h2 = 0; h2 < 2; ++h2)
                af[m][h2] = fragswz(As, wr * 64 + m * 16 + lq, h2 * 64 + g * 16);
        #pragma unroll
        for (int n = 0; n < WN; ++n)
            #pragma unroll
            for (int h2 = 0; h2 < 2; ++h2)
                bfr[n][h2] = fragswz(Bs, wc * (WN * 16) + n * 16 + lq, h2 * 64 + g * 16);

        #pragma unroll
        for (int m = 0; m < 4; ++m)
            #pragma unroll
            for (int n = 0; n < WN; ++n)
                #pragma unroll
                for (int h2 = 0; h2 < 2; ++h2)
                    acc[m][n] = __builtin_amdgcn_mfma_f32_16x16x32_bf16(
                        af[m][h2], bfr[n][h2], acc[m][n], 0, 0, 0);
        __syncthreads();
    }

    const int seg = n0 >> 10;
    const float* bp = (seg == 0) ? b0 : ((seg == 1) ? b1 : b2);
    const float bsc = (seg == 0) ? s0 : 1.f;

    #pragma unroll
    for (int m = 0; m < 4; ++m) {
        #pragma unroll
        for (int n = 0; n < WN; ++n) {
            int rbase = m0 + wr * 64 + m * 16 + (g << 2);
            int col = n0 + wc * (WN * 16) + n * 16 + lq;
            float bv = bp[col - (seg << 10)] * bsc;
            #pragma unroll
            for (int r = 0; r < 4; ++r) {
                float v = acc[m][n][r] + bv;
                int rr = rbase + r;
                if (OUT_F32) {
                    ((float*)Cv)[(size_t)rr * N + col] = v;
                } else {
                    // chunk-swizzle by row within each 64-col group
                    int col2 = (col & ~63) | (col & 7) |
                               ((((col >> 3) & 7) ^ (rr & 7)) << 3);
                    ((bf16*)Cv)[(size_t)rr * N + col2] = (bf16)v;
                }
            }
        }
    }
}

// ---------------- fused decay-masked attention (R5 skeleton, KT=128, gload-K) ----
// 512 blocks = (h, qblk64, batch-pair); 4 waves x 16 q-rows; 8 k-tiles x 2 bi
// = 16 compute stages, one barrier each. K staged via global_load_lds (qkv is
// stored row-chunk-swizzled so linear gload + fragswz reads are correct).
// V^T reg-staged as two verified 64x64 sub-tiles. No-max softmax.
struct VR { u16x8 v[4]; };

__device__ __forceinline__ void vload(VR& r, const bf16* qkv, int grow0, int voff, int tid) {
    const int kp = tid >> 3, o = tid & 7;
    #pragma unroll
    for (int p = 0; p < 2; ++p)
        #pragma unroll
        for (int e = 0; e < 2; ++e) {
            int grow = grow0 + ((p * 32 + kp) << 1) + e;
            int chunk = o ^ (grow & 7);   // undo storage swizzle -> logical octet o
            r.v[2 * p + e] = *reinterpret_cast<const u16x8*>(
                &qkv[(size_t)grow * 3072 + voff + (chunk << 3)]);
        }
}

__device__ __forceinline__ void write_v(const VR& r, bf16* Vb, int tid) {
    const int kp = tid >> 3, o = tid & 7;
    #pragma unroll
    for (int p = 0; p < 2; ++p) {
        char* vb = reinterpret_cast<char*>(Vb + p * 64 * 64);
        #pragma unroll
        for (int j = 0; j < 8; ++j) {
            int d = (o << 3) + j;
            int byteo = d * 128 + ((kp << 2) ^ ((d & 7) << 4));
            unsigned int w = (unsigned int)r.v[2 * p][j] | ((unsigned int)r.v[2 * p + 1][j] << 16);
            *reinterpret_cast<unsigned int*>(vb + byteo) = w;
        }
    }
}

__device__ __forceinline__ void kstage(const bf16* qkv, int grow0, int koff,
                                       bf16* Kb, int wid, int lane) {
    #pragma unroll
    for (int p = 0; p < 4; ++p) {
        int rb = wid * 32 + p * 8;
        gload16(&qkv[(size_t)(grow0 + rb + (lane >> 3)) * 3072 + koff + ((lane & 7) << 3)],
                &Kb[rb * 64]);
    }
}

__device__ __forceinline__ void compute_tile(
    const bf16* Kb, const bf16* Vb, bf16* Pw,
    const float4 (&mreg)[8], const bf16x8 (&aqb)[2],
    f32x4& lacc, f32x4 (&oacc)[4], int lane)
{
    const int lq = lane & 15, g = lane >> 4;
    f32x4 sacc[8];
    #pragma unroll
    for (int ct = 0; ct < 8; ++ct) sacc[ct] = (f32x4){0.f, 0.f, 0.f, 0.f};
    #pragma unroll
    for (int ct = 0; ct < 8; ++ct)
        #pragma unroll
        for (int h2 = 0; h2 < 2; ++h2)
            sacc[ct] = __builtin_amdgcn_mfma_f32_16x16x32_bf16(
                fragswz(Kb, ct * 16 + lq, h2 * 64 + g * 16), aqb[h2], sacc[ct], 0, 0, 0);

    const int px = (lq & 7) << 4;
    // p = exp2(s * mask); accumulate row-sum; pack P per k-sub-tile
    #pragma unroll
    for (int s = 0; s < 2; ++s) {
        char* pb8 = reinterpret_cast<char*>(Pw + s * 16 * 64);
        #pragma unroll
        for (int c = 0; c < 4; ++c) {
            int ct = s * 4 + c;
            float p0 = __builtin_exp2f(sacc[ct][0] * mreg[ct].x);
            float p1 = __builtin_exp2f(sacc[ct][1] * mreg[ct].y);
            float p2 = __builtin_exp2f(sacc[ct][2] * mreg[ct].z);
            float p3 = __builtin_exp2f(sacc[ct][3] * mreg[ct].w);
            lacc[0] += p0; lacc[1] += p1; lacc[2] += p2; lacc[3] += p3;
            bf16x4 pbv;
            pbv[0] = (bf16)p0; pbv[1] = (bf16)p1; pbv[2] = (bf16)p2; pbv[3] = (bf16)p3;
            *reinterpret_cast<bf16x4*>(pb8 + lq * 128 + (((c << 5) + (g << 3)) ^ px)) = pbv;
        }
    }

    // O^T += V^T . P over both k-subs
    #pragma unroll
    for (int s = 0; s < 2; ++s) {
        const char* vb = reinterpret_cast<const char*>(Vb + s * 64 * 64);
        const char* pb8 = reinterpret_cast<const char*>(Pw + s * 16 * 64);
        bf16x8 pf[2];
        #pragma unroll
        for (int h2 = 0; h2 < 2; ++h2)
            pf[h2] = *reinterpret_cast<const bf16x8*>(pb8 + lq * 128 + ((h2 * 64 + g * 16) ^ px));
        #pragma unroll
        for (int ot = 0; ot < 4; ++ot) {
            #pragma unroll
            for (int h2 = 0; h2 < 2; ++h2) {
                int d = ot * 16 + lq;
                int kb = h2 * 64 + g * 16;
                bf16x8 vf = *reinterpret_cast<const bf16x8*>(vb + d * 128 + (kb ^ ((d & 7) << 4)));
                oacc[ot] = __builtin_amdgcn_mfma_f32_16x16x32_bf16(vf, pf[h2], oacc[ot], 0, 0, 0);
            }
        }
    }
}

__global__ __launch_bounds__(256) void attn_kernel(
    const bf16* __restrict__ qkv, const float* __restrict__ mask, bf16* __restrict__ Og)
{
    __shared__ __align__(16) bf16 Kbuf[2][KT * 64];        // 16 KB x2
    __shared__ __align__(16) bf16 Vbuf[2][2][64 * 64];     // 8 KB x4
    __shared__ __align__(16) bf16 Ps[4][2][16 * 64];       // 2 KB x8 -> 80 KB total

    const int bid = blockIdx.x;
    const int xcd = bid & 7, slot = bid >> 3;
    const int pg = xcd * 32 + (slot >> 1);
    const int bp = slot & 1;
    const int h = pg >> 4, qblk = pg & 15;

    const int tid = threadIdx.x, lane = tid & 63, wid = tid >> 6;
    const int lq = lane & 15, g = lane >> 4;
    const int q = (qblk << 6) + wid * 16 + lq;
    const int koff = 1024 + h * HEADDIM, voff = 2048 + h * HEADDIM, qoff = h * HEADDIM;
    const int b0 = bp * 2, b1 = bp * 2 + 1;
    const float* mh = mask + (size_t)h * SEQ * SEQ + (size_t)q * SEQ;

    // Q fragments from swizzled qkv (pre-scaled by QSCALE via wq)
    bf16x8 aq[2][2];
    #pragma unroll
    for (int bi = 0; bi < 2; ++bi)
        #pragma unroll
        for (int h2 = 0; h2 < 2; ++h2) {
            int chunk = (h2 * 4 + g) ^ (q & 7);
            aq[bi][h2] = *reinterpret_cast<const bf16x8*>(
                &qkv[(size_t)((b0 + bi) * SEQ + q) * 3072 + qoff + (chunk << 3)]);
        }

    f32x4 lacc[2] = {};
    f32x4 oacc[2][4] = {};

    // prologue: tile 0 for both batches
    kstage(qkv, b0 * SEQ, koff, Kbuf[0], wid, lane);
    kstage(qkv, b1 * SEQ, koff, Kbuf[1], wid, lane);
    VR s0, s1;
    vload(s0, qkv, b0 * SEQ, voff, tid);
    vload(s1, qkv, b1 * SEQ, voff, tid);
    write_v(s0, Vbuf[0][0], tid);
    write_v(s1, Vbuf[1][0], tid);
    __syncthreads();

    for (int t = 0; t < 8; ++t) {
        // mask tile t (shared by both batches of the pair)
        float4 mreg[8];
        #pragma unroll
        for (int ct = 0; ct < 8; ++ct)
            mreg[ct] = *reinterpret_cast<const float4*>(&mh[t * KT + ct * 16 + (g << 2)]);

        // --- stage A: bi=0, reads Kbuf[0]/Vbuf[0] ---
        if (t >= 1) {
            kstage(qkv, b1 * SEQ + t * KT, koff, Kbuf[1], wid, lane);  // for stage B
            write_v(s1, Vbuf[1][0], tid);                               // (b1, t)
        }
        if (t < 7) vload(s0, qkv, b0 * SEQ + (t + 1) * KT, voff, tid);
        compute_tile(Kbuf[0], Vbuf[0][0], Ps[wid][0], mreg, aq[0], lacc[0], oacc[0], lane);
        __syncthreads();

        // --- stage B: bi=1, reads Kbuf[1]/Vbuf[1] ---
        if (t < 7) {
            kstage(qkv, b0 * SEQ + (t + 1) * KT, koff, Kbuf[0], wid, lane);
            vload(s1, qkv, b1 * SEQ + (t + 1) * KT, voff, tid);
            write_v(s0, Vbuf[0][0], tid);                               // (b0, t+1)
        }
        compute_tile(Kbuf[1], Vbuf[1][0], Ps[wid][0], mreg, aq[1], lacc[1], oacc[1], lane);
        __syncthreads();
    }

    // epilogue: reduce l across the 4 lane-groups, store O (chunk-swizzled for GEMM)
    #pragma unroll
    for (int bi = 0; bi < 2; ++bi) {
        float lsum = lacc[bi][0] + lacc[bi][1] + lacc[bi][2] + lacc[bi][3];
        lsum += __shfl_xor(lsum, 16, 64);
        lsum += __shfl_xor(lsum, 32, 64);
        float inv = 1.f / lsum;
        #pragma unroll
        for (int ot = 0; ot < 4; ++ot) {
            bf16x4 o;
            o[0] = (bf16)(oacc[bi][ot][0] * inv);
            o[1] = (bf16)(oacc[bi][ot][1] * inv);
            o[2] = (bf16)(oacc[bi][ot][2] * inv);
            o[3] = (bf16)(oacc[bi][ot][3] * inv);
            int lcol = ot * 16 + (g << 2);
            int chunk = (lcol >> 3) ^ (q & 7);
            int col = h * HEADDIM + (chunk << 3) + (lcol & 7);
            *reinterpret_cast<bf16x4*>(
                &Og[(size_t)((b0 + bi) * SEQ + q) * DIMSZ + col]) = o;
        }
    }
}

extern "C" void kernel_launch(void* const* d_in, const int* in_sizes, int n_in,
                              void* d_out, int out_size, void* d_ws, size_t ws_size,
                              hipStream_t stream) {
    const float* x    = (const float*)d_in[0];
    const float* mask = (const float*)d_in[1];
    const float* wq   = (const float*)d_in[2];
    const float* bq   = (const float*)d_in[3];
    const float* wk   = (const float*)d_in[4];
    const float* bk   = (const float*)d_in[5];
    const float* wv   = (const float*)d_in[6];
    const float* bv   = (const float*)d_in[7];
    const float* wo   = (const float*)d_in[8];
    const float* bo   = (const float*)d_in[9];
    float* out = (float*)d_out;

    char* ws = (char*)d_ws;
    bf16* xb    = (bf16*)ws; ws += (size_t)MTOK * DIMSZ * 2;         // 8 MB
    bf16* wqkvb = (bf16*)ws; ws += (size_t)3 * DIMSZ * DIMSZ * 2;    // 6 MB
    bf16* wob   = (bf16*)ws; ws += (size_t)DIMSZ * DIMSZ * 2;        // 2 MB
    bf16* qkv   = (bf16*)ws; ws += (size_t)MTOK * 3 * DIMSZ * 2;     // 24 MB
    bf16* aob   = (bf16*)ws; ws += (size_t)MTOK * DIMSZ * 2;         // 8 MB -> 48 MB

    int n4x = (int)((size_t)MTOK * DIMSZ / 4);
    cvt_swz<<<(n4x + 255) / 256, 256, 0, stream>>>((const float4*)x, xb, n4x, 1.f);
    cvt_weights<<<(4 * 262144) / 256, 256, 0, stream>>>(
        (const float4*)wq, (const float4*)wk, (const float4*)wv, (const float4*)wo,
        wqkvb, wob);

    // fused QKV projection -> qkv (bf16, row-chunk-swizzled)
    gemm_glds<4, 0><<<(MTOK / 128) * (3 * DIMSZ / 128), 256, 0, stream>>>(
        xb, wqkvb, bq, bk, bv, QSCALE, qkv, MTOK, 3 * DIMSZ, DIMSZ);

    // fused attention -> aob (bf16, row-chunk-swizzled)
    attn_kernel<<<512, 256, 0, stream>>>(qkv, mask, aob);

    // output projection -> out (fp32, linear)
    gemm_glds<2, 1><<<(MTOK / 128) * (DIMSZ / 64), 256, 0, stream>>>(
        aob, wob, bo, bo, bo, 1.f, out, MTOK, DIMSZ, DIMSZ);
}

// Round 9
// 113.577 us; speedup vs baseline: 3.0365x; 1.2206x over previous
//
#include <hip/hip_runtime.h>
#include <hip/hip_bf16.h>
#include <math.h>

typedef __bf16 bf16;
typedef __bf16 bf16x8 __attribute__((ext_vector_type(8)));
typedef __bf16 bf16x4 __attribute__((ext_vector_type(4)));
typedef float f32x4 __attribute__((ext_vector_type(4)));
typedef unsigned short u16;
typedef u16 u16x8 __attribute__((ext_vector_type(8)));

#define SEQ 1024
#define DIMSZ 1024
#define NHEADS 16
#define HEADDIM 64
#define BATCH 4
#define MTOK (BATCH * SEQ)

// q-scale: 1/sqrt(64) * log2(e)  (log2e folded so softmax uses raw exp2)
#define QSCALE 0.180336880f

// ---------------- async global->LDS (16B per lane, linear dest) ----------------
typedef __attribute__((address_space(1))) const unsigned char gas_u8;
typedef __attribute__((address_space(3))) unsigned char las_u8;
__device__ __forceinline__ void gload16(const void* g, void* l) {
    __builtin_amdgcn_global_load_lds((const gas_u8*)g, (las_u8*)l, 16, 0, 0);
}

// ---------------- fp32 -> bf16 conversion with baked chunk-swizzle ----------------
// dst element (row, col) stored at chunk ^= (row&7) within each 64-col group
__device__ __forceinline__ void cvt_store(const float4 v, bf16* dst, int e0, float scale) {
    int row = e0 >> 10, col = e0 & 1023;
    int col2 = (col & ~63) | (col & 7) | (((((col >> 3) & 7) ^ (row & 7))) << 3);
    bf16x4 o;
    o[0] = (bf16)(v.x * scale);
    o[1] = (bf16)(v.y * scale);
    o[2] = (bf16)(v.z * scale);
    o[3] = (bf16)(v.w * scale);
    *reinterpret_cast<bf16x4*>(&dst[(size_t)row * 1024 + col2]) = o;
}

// single merged conversion launch: x -> xb; wq(*QSCALE),wk,wv -> wqkvb; wo -> wob
__global__ void cvt_all(const float4* __restrict__ x,
                        const float4* __restrict__ wq, const float4* __restrict__ wk,
                        const float4* __restrict__ wv, const float4* __restrict__ wo,
                        bf16* __restrict__ xb, bf16* __restrict__ wqkvb,
                        bf16* __restrict__ wob) {
    int i = blockIdx.x * blockDim.x + threadIdx.x;   // 0 .. 2*1048576-1
    if (i < 1048576) {
        cvt_store(x[i], xb, i << 2, 1.f);
    } else {
        int li = i - 1048576;
        int mat = li >> 18, lj = li & 262143;
        const float4* s = (mat == 0) ? wq : (mat == 1) ? wk : (mat == 2) ? wv : wo;
        bf16* d = (mat < 3) ? (wqkvb + (size_t)mat * 1024 * 1024) : wob;
        cvt_store(s[lj], d, lj << 2, (mat == 0) ? QSCALE : 1.f);
    }
}

// swizzled LDS fragment read from linear [rows][64] bf16 tile (128B rows)
__device__ __forceinline__ bf16x8 fragswz(const bf16* base, int row, int kb) {
    return *reinterpret_cast<const bf16x8*>(
        reinterpret_cast<const char*>(base) + row * 128 + (kb ^ ((row & 7) << 4)));
}

// padded-LDS fragment read (LDT=72) used by attn
#define LDT 72
__device__ __forceinline__ bf16x8 ldsfrag72(const bf16* base, int row0, int k0, int lane) {
    return *reinterpret_cast<const bf16x8*>(base + (row0 + (lane & 15)) * LDT + k0 + ((lane >> 4) << 3));
}

// ---------------- m97-style GEMM: C[M][N] = A[M][K] @ B[N][K]^T + bias ----------------
// A, B stored pre-swizzled. Linear output (fp32 or bf16). No setprio (m190).
template <int WN, int OUT_F32>
__global__ __launch_bounds__(256) void gemm_glds(
    const bf16* __restrict__ A, const bf16* __restrict__ Bm,
    const float* __restrict__ b0, const float* __restrict__ b1, const float* __restrict__ b2,
    float s0, void* __restrict__ Cv, int M, int N, int K)
{
    __shared__ __align__(16) bf16 As[128 * 64];
    __shared__ __align__(16) bf16 Bs[WN * 32 * 64];

    const int BN = WN * 32;
    const int nbn = N / BN;
    const int wrk = (blockIdx.x & 7) * ((int)gridDim.x >> 3) + (blockIdx.x >> 3);
    const int bm = wrk / nbn, bn = wrk % nbn;
    const int m0 = bm << 7, n0 = bn * BN;
    const int tid = threadIdx.x, lane = tid & 63, wid = tid >> 6;
    const int wr = wid >> 1, wc = wid & 1;
    const int lq = lane & 15, g = lane >> 4;

    f32x4 acc[4][WN];
    #pragma unroll
    for (int m = 0; m < 4; ++m)
        #pragma unroll
        for (int n = 0; n < WN; ++n)
            acc[m][n] = (f32x4){0.f, 0.f, 0.f, 0.f};

    for (int kt = 0; kt < K; kt += 64) {
        #pragma unroll
        for (int i = 0; i < 4; ++i) {
            int rb = wid * 32 + i * 8;
            gload16(&A[(size_t)(m0 + rb + (lane >> 3)) * K + kt + ((lane & 7) << 3)],
                    &As[rb * 64]);
        }
        #pragma unroll
        for (int i = 0; i < WN; ++i) {
            int rb = wid * (WN * 8) + i * 8;
            gload16(&Bm[(size_t)(n0 + rb + (lane >> 3)) * K + kt + ((lane & 7) << 3)],
                    &Bs[rb * 64]);
        }
        __syncthreads();

        bf16x8 af[4][2], bfr[WN][2];
        #pragma unroll
        for (int m = 0; m < 4; ++m)
            #pragma unroll
            for (int h2 = 0; h2 < 2; ++h2)
                af[m][h2] = fragswz(As, wr * 64 + m * 16 + lq, h2 * 64 + g * 16);
        #pragma unroll
        for (int n = 0; n < WN; ++n)
            #pragma unroll
            for (int h2 = 0; h2 < 2; ++h2)
                bfr[n][h2] = fragswz(Bs, wc * (WN * 16) + n * 16 + lq, h2 * 64 + g * 16);

        #pragma unroll
        for (int m = 0; m < 4; ++m)
            #pragma unroll
            for (int n = 0; n < WN; ++n)
                #pragma unroll
                for (int h2 = 0; h2 < 2; ++h2)
                    acc[m][n] = __builtin_amdgcn_mfma_f32_16x16x32_bf16(
                        af[m][h2], bfr[n][h2], acc[m][n], 0, 0, 0);
        __syncthreads();
    }

    const int seg = n0 >> 10;
    const float* bp = (seg == 0) ? b0 : ((seg == 1) ? b1 : b2);
    const float bsc = (seg == 0) ? s0 : 1.f;

    #pragma unroll
    for (int m = 0; m < 4; ++m) {
        #pragma unroll
        for (int n = 0; n < WN; ++n) {
            int rbase = m0 + wr * 64 + m * 16 + (g << 2);
            int col = n0 + wc * (WN * 16) + n * 16 + lq;
            float bv = bp[col - (seg << 10)] * bsc;
            #pragma unroll
            for (int r = 0; r < 4; ++r) {
                float v = acc[m][n][r] + bv;
                if (OUT_F32)
                    ((float*)Cv)[(size_t)(rbase + r) * N + col] = v;
                else
                    ((bf16*)Cv)[(size_t)(rbase + r) * N + col] = (bf16)v;
            }
        }
    }
}

// ---------------- fused decay-masked attention (R5 structure, NO setprio) ----------
// 512 blocks = (h, qblk64, batch-pair); 4 waves x 16 q-rows; 32-stage pipeline,
// one barrier per stage; mask regs shared across the batch pair; no-max softmax.
struct KVRegs { bf16x8 k0, k1; u16x8 v0, v1; };

__device__ __forceinline__ void issue_loads(KVRegs& r, const bf16* qkv, int brow,
                                            int koff, int voff, int tid) {
    const int rK = tid >> 3, o8 = (tid & 7) << 3;
    r.k0 = *reinterpret_cast<const bf16x8*>(&qkv[(size_t)(brow + rK) * 3072 + koff + o8]);
    r.k1 = *reinterpret_cast<const bf16x8*>(&qkv[(size_t)(brow + rK + 32) * 3072 + koff + o8]);
    const int rV = rK << 1;
    r.v0 = *reinterpret_cast<const u16x8*>(&qkv[(size_t)(brow + rV) * 3072 + voff + o8]);
    r.v1 = *reinterpret_cast<const u16x8*>(&qkv[(size_t)(brow + rV + 1) * 3072 + voff + o8]);
}

__device__ __forceinline__ void write_stage(const KVRegs& r, bf16* Kb, bf16* Vb, int tid) {
    const int rK = tid >> 3, o = tid & 7, o8 = o << 3;
    *reinterpret_cast<bf16x8*>(&Kb[rK * LDT + o8]) = r.k0;
    *reinterpret_cast<bf16x8*>(&Kb[(rK + 32) * LDT + o8]) = r.k1;
    const int rV = rK << 1;
    char* vb = reinterpret_cast<char*>(Vb);
    #pragma unroll
    for (int j = 0; j < 8; ++j) {
        int d = o8 + j;
        int byteo = (d * 144 + rV * 2) ^ (o << 4);
        unsigned int w = (unsigned int)r.v0[j] | ((unsigned int)r.v1[j] << 16);
        *reinterpret_cast<unsigned int*>(vb + byteo) = w;
    }
}

// No-max softmax: |s| <= ~8.6 (log2-domain), mask in [0,1] -> exp2 safe without
// max subtraction; row-sum accumulated per-lane, reduced once in epilogue.
__device__ __forceinline__ void compute_stage(
    const bf16* Kb, const bf16* Vb, bf16* Psw,
    const float4 (&mreg)[4], const bf16x8 (&aqb)[2],
    f32x4& lacc, f32x4 (&oacc)[4], int lane)
{
    const int lq = lane & 15, g = lane >> 4;
    f32x4 sacc[4];
    #pragma unroll
    for (int ct = 0; ct < 4; ++ct) sacc[ct] = (f32x4){0.f, 0.f, 0.f, 0.f};
    #pragma unroll
    for (int ct = 0; ct < 4; ++ct)
        #pragma unroll
        for (int h2 = 0; h2 < 2; ++h2)
            sacc[ct] = __builtin_amdgcn_mfma_f32_16x16x32_bf16(
                ldsfrag72(Kb, ct * 16, h2 * 32, lane), aqb[h2], sacc[ct], 0, 0, 0);

    // p = exp2(s * mask); accumulate row-sum; pack P
    #pragma unroll
    for (int ct = 0; ct < 4; ++ct) {
        float p0 = __builtin_exp2f(sacc[ct][0] * mreg[ct].x);
        float p1 = __builtin_exp2f(sacc[ct][1] * mreg[ct].y);
        float p2 = __builtin_exp2f(sacc[ct][2] * mreg[ct].z);
        float p3 = __builtin_exp2f(sacc[ct][3] * mreg[ct].w);
        lacc[0] += p0; lacc[1] += p1; lacc[2] += p2; lacc[3] += p3;
        bf16x4 pbv;
        pbv[0] = (bf16)p0; pbv[1] = (bf16)p1; pbv[2] = (bf16)p2; pbv[3] = (bf16)p3;
        *reinterpret_cast<bf16x4*>(&Psw[lq * LDT + ct * 16 + (g << 2)]) = pbv;
    }

    // O^T += mfma(V^T rows d, P rows q)
    const char* vb = reinterpret_cast<const char*>(Vb);
    #pragma unroll
    for (int ot = 0; ot < 4; ++ot) {
        #pragma unroll
        for (int h2 = 0; h2 < 2; ++h2) {
            int d = ot * 16 + lq;
            int byteo = (d * 144 + (h2 * 32 + g * 8) * 2) ^ (((d >> 3) & 7) << 4);
            bf16x8 vf = *reinterpret_cast<const bf16x8*>(vb + byteo);
            bf16x8 pf = *reinterpret_cast<const bf16x8*>(&Psw[lq * LDT + h2 * 32 + g * 8]);
            oacc[ot] = __builtin_amdgcn_mfma_f32_16x16x32_bf16(vf, pf, oacc[ot], 0, 0, 0);
        }
    }
}

__global__ __launch_bounds__(256) void attn_kernel(
    const bf16* __restrict__ qkv, const float* __restrict__ mask, bf16* __restrict__ Og)
{
    __shared__ __align__(16) bf16 Kbuf[2][64 * LDT];
    __shared__ __align__(16) bf16 Vbuf[2][64 * LDT];
    __shared__ __align__(16) bf16 Ps[4][16 * LDT];

    const int bid = blockIdx.x;
    const int xcd = bid & 7, slot = bid >> 3;
    const int pg = xcd * 32 + (slot >> 1);
    const int bp = slot & 1;
    const int h = pg >> 4, qblk = pg & 15;

    const int tid = threadIdx.x, lane = tid & 63, wid = tid >> 6;
    const int lq = lane & 15, g = lane >> 4;
    const int q = (qblk << 6) + wid * 16 + lq;
    const int koff = 1024 + h * HEADDIM, voff = 2048 + h * HEADDIM, qoff = h * HEADDIM;
    const float* mh = mask + (size_t)h * SEQ * SEQ + (size_t)q * SEQ;

    // Q fragments (pre-scaled by QSCALE via wq)
    bf16x8 aq[2][2];
    #pragma unroll
    for (int bi = 0; bi < 2; ++bi)
        #pragma unroll
        for (int h2 = 0; h2 < 2; ++h2)
            aq[bi][h2] = *reinterpret_cast<const bf16x8*>(
                &qkv[(size_t)((bp * 2 + bi) * SEQ + q) * 3072 + qoff + h2 * 32 + g * 8]);

    f32x4 lacc[2] = {};
    f32x4 oacc[2][4] = {};

    // prologue
    KVRegs s0, s1;
    issue_loads(s0, qkv, (bp * 2 + 0) * SEQ, koff, voff, tid);
    issue_loads(s1, qkv, (bp * 2 + 1) * SEQ, koff, voff, tid);
    float4 mregA[4], mregB[4];
    #pragma unroll
    for (int ct = 0; ct < 4; ++ct) {
        mregA[ct] = *reinterpret_cast<const float4*>(&mh[ct * 16 + (g << 2)]);
        mregB[ct] = *reinterpret_cast<const float4*>(&mh[64 + ct * 16 + (g << 2)]);
    }
    write_stage(s0, Kbuf[0], Vbuf[0], tid);
    __syncthreads();

    for (int t = 0; t < 16; ++t) {
        // --- stage (t, bi=0) from buf0 ---
        if (t < 15) issue_loads(s0, qkv, (bp * 2 + 0) * SEQ + (t + 1) * 64, koff, voff, tid);
        compute_stage(Kbuf[0], Vbuf[0], Ps[wid], mregA, aq[0], lacc[0], oacc[0], lane);
        write_stage(s1, Kbuf[1], Vbuf[1], tid);
        __syncthreads();

        // --- stage (t, bi=1) from buf1 ---
        if (t < 15) issue_loads(s1, qkv, (bp * 2 + 1) * SEQ + (t + 1) * 64, koff, voff, tid);
        compute_stage(Kbuf[1], Vbuf[1], Ps[wid], mregA, aq[1], lacc[1], oacc[1], lane);
        #pragma unroll
        for (int ct = 0; ct < 4; ++ct) mregA[ct] = mregB[ct];
        if (t < 14)
            #pragma unroll
            for (int ct = 0; ct < 4; ++ct)
                mregB[ct] = *reinterpret_cast<const float4*>(&mh[(t + 2) * 64 + ct * 16 + (g << 2)]);
        if (t < 15) write_stage(s0, Kbuf[0], Vbuf[0], tid);
        __syncthreads();
    }

    // epilogue: single cross-lane l reduction, then O stores (chunk-swizzled for GEMM)
    #pragma unroll
    for (int bi = 0; bi < 2; ++bi) {
        float lsum = lacc[bi][0] + lacc[bi][1] + lacc[bi][2] + lacc[bi][3];
        lsum += __shfl_xor(lsum, 16, 64);
        lsum += __shfl_xor(lsum, 32, 64);
        float inv = 1.f / lsum;
        #pragma unroll
        for (int ot = 0; ot < 4; ++ot) {
            bf16x4 o;
            o[0] = (bf16)(oacc[bi][ot][0] * inv);
            o[1] = (bf16)(oacc[bi][ot][1] * inv);
            o[2] = (bf16)(oacc[bi][ot][2] * inv);
            o[3] = (bf16)(oacc[bi][ot][3] * inv);
            int lcol = ot * 16 + (g << 2);
            int chunk = (lcol >> 3) ^ (q & 7);
            int col = h * HEADDIM + (chunk << 3) + (lcol & 7);
            *reinterpret_cast<bf16x4*>(
                &Og[(size_t)((bp * 2 + bi) * SEQ + q) * DIMSZ + col]) = o;
        }
    }
}

extern "C" void kernel_launch(void* const* d_in, const int* in_sizes, int n_in,
                              void* d_out, int out_size, void* d_ws, size_t ws_size,
                              hipStream_t stream) {
    const float* x    = (const float*)d_in[0];
    const float* mask = (const float*)d_in[1];
    const float* wq   = (const float*)d_in[2];
    const float* bq   = (const float*)d_in[3];
    const float* wk   = (const float*)d_in[4];
    const float* bk   = (const float*)d_in[5];
    const float* wv   = (const float*)d_in[6];
    const float* bv   = (const float*)d_in[7];
    const float* wo   = (const float*)d_in[8];
    const float* bo   = (const float*)d_in[9];
    float* out = (float*)d_out;

    char* ws = (char*)d_ws;
    bf16* xb    = (bf16*)ws; ws += (size_t)MTOK * DIMSZ * 2;         // 8 MB
    bf16* wqkvb = (bf16*)ws; ws += (size_t)3 * DIMSZ * DIMSZ * 2;    // 6 MB
    bf16* wob   = (bf16*)ws; ws += (size_t)DIMSZ * DIMSZ * 2;        // 2 MB
    bf16* qkv   = (bf16*)ws; ws += (size_t)MTOK * 3 * DIMSZ * 2;     // 24 MB
    bf16* aob   = (bf16*)ws; ws += (size_t)MTOK * DIMSZ * 2;         // 8 MB -> 48 MB

    // single conversion launch (x + all four weights)
    cvt_all<<<(2 * 1048576) / 256, 256, 0, stream>>>(
        (const float4*)x, (const float4*)wq, (const float4*)wk,
        (const float4*)wv, (const float4*)wo, xb, wqkvb, wob);

    // fused QKV projection: [4096,1024] @ [3072,1024]^T -> [4096,3072] (linear bf16)
    gemm_glds<4, 0><<<(MTOK / 128) * (3 * DIMSZ / 128), 256, 0, stream>>>(
        xb, wqkvb, bq, bk, bv, QSCALE, qkv, MTOK, 3 * DIMSZ, DIMSZ);

    // fused attention -> aob (bf16, chunk-swizzled for the final GEMM)
    attn_kernel<<<512, 256, 0, stream>>>(qkv, mask, aob);

    // output projection: [4096,1024] @ [1024,1024]^T -> [4096,1024] fp32
    gemm_glds<2, 1><<<(MTOK / 128) * (DIMSZ / 64), 256, 0, stream>>>(
        aob, wob, bo, bo, bo, 1.f, out, MTOK, DIMSZ, DIMSZ);
}